// Round 11
// baseline (359.216 us; speedup 1.0000x reference)
//
#include <hip/hip_runtime.h>
#include <hip/hip_bf16.h>

#define B_ 4096
#define T_ 4
#define D_ 1024
#define E_ 4

typedef unsigned short ushort_t;
typedef float f32x4 __attribute__((ext_vector_type(4)));
typedef short bf16x8 __attribute__((ext_vector_type(8)));

__device__ __forceinline__ unsigned short f2bf(float f) {
    unsigned int u = __float_as_uint(f);
    u += 0x7FFF + ((u >> 16) & 1);   // round-to-nearest-even
    return (unsigned short)(u >> 16);
}

#define GLOBAL_LOAD_LDS16(gp, lp)                                                        \
    __builtin_amdgcn_global_load_lds((const __attribute__((address_space(1))) void*)(gp),\
                                     (__attribute__((address_space(3))) void*)(lp),      \
                                     16, 0, 0)

// Fused prep, one launch. Flat grid: blk<4096 -> W transpose (16 matrices x
// 256 64x64 tiles); blk>=4096 -> x convert (8192 chunks of 2048 f32).
// Round-6 version ran 59us @ 28% HBM peak (scalar 2B stores, 16B/thread
// convert). This version: float4 loads + 16B bf16x8 stores both paths.
__global__ __launch_bounds__(256) void k_prep(const float* __restrict__ x,
                                              const float* __restrict__ W1,
                                              const float* __restrict__ W2,
                                              ushort_t* __restrict__ hbf,
                                              ushort_t* __restrict__ W1t,
                                              ushort_t* __restrict__ W2t) {
    const int blk = blockIdx.x;
    const int tid = threadIdx.x;
    if (blk >= 4096) {
        // convert: x [B,T,D] f32 -> hbf [T,B,D] bf16; 2048 f32 per block
        const int base = ((blk - 4096) * 256 + tid) * 8;
        const float4 v0 = *(const float4*)(x + base);
        const float4 v1 = *(const float4*)(x + base + 4);
        bf16x8 o;
        o[0] = (short)f2bf(v0.x); o[1] = (short)f2bf(v0.y);
        o[2] = (short)f2bf(v0.z); o[3] = (short)f2bf(v0.w);
        o[4] = (short)f2bf(v1.x); o[5] = (short)f2bf(v1.y);
        o[6] = (short)f2bf(v1.z); o[7] = (short)f2bf(v1.w);
        const int d = base & (D_ - 1);
        const int t = (base >> 10) & 3;
        const int b = base >> 12;
        *(bf16x8*)(hbf + (size_t)t * B_ * D_ + (size_t)b * D_ + d) = o;
        return;
    }
    // transpose: W[z] [D,O] f32 -> Wt[z] [O,D] bf16, 64x64 tile per block
    const int z = blk >> 8;                 // 0..15
    const int ti = blk & 255;               // 16x16 tile grid
    const int o0 = (ti & 15) * 64, d0 = (ti >> 4) * 64;
    const float* src = (z < 8) ? (W1 + (size_t)z * D_ * D_) : (W2 + (size_t)(z - 8) * D_ * D_);
    ushort_t* dst = (z < 8) ? (W1t + (size_t)z * D_ * D_) : (W2t + (size_t)(z - 8) * D_ * D_);

    __shared__ float tile[64][65];
    // load: 64 rows(d) x 64 cols(o) f32 as float4; 4 rows-of-16-float4/thread
    const int c4 = tid & 15;                // float4 column 0..15
    const int r0 = tid >> 4;                // 0..15
#pragma unroll
    for (int j = 0; j < 4; ++j) {
        const int r = r0 + 16 * j;
        const float4 v = *(const float4*)(src + (size_t)(d0 + r) * D_ + o0 + c4 * 4);
        tile[r][c4 * 4 + 0] = v.x;
        tile[r][c4 * 4 + 1] = v.y;
        tile[r][c4 * 4 + 2] = v.z;
        tile[r][c4 * 4 + 3] = v.w;
    }
    __syncthreads();
    // store: 64 rows(o) x 64 cols(d) bf16 as bf16x8 (16B); 2 rows-of-8/thread
    const int cg = tid & 7, ro = tid >> 3;  // cg: 8-col group, ro: 0..31
#pragma unroll
    for (int j = 0; j < 2; ++j) {
        const int o = ro + 32 * j;
        bf16x8 ov;
#pragma unroll
        for (int k = 0; k < 8; ++k) ov[k] = (short)f2bf(tile[cg * 8 + k][o]);
        *(bf16x8*)(dst + (size_t)(o0 + o) * D_ + d0 + cg * 8) = ov;
    }
}

// C[4096,1024] = relu(A * Bt^T + bias) [* scale], batched over tasks.
// 256x256 tile, BK=64, 8 waves (2M x 4N), 128 KiB LDS double-buffer.
// 4 phases/K-tile {ds_read subtile | stage half-tile | s_barrier | setprio(1)
// 16xMFMA setprio(0) | s_barrier}; ONE counted s_waitcnt vmcnt(4) per K-tile,
// T2 XOR swizzle (LDS dest linear, global source pre-swizzled, reads swizzled).
// [round-3 verified: 43.5us/dispatch, 790 TF. round-5 static-dbuf 2x-unroll
//  REGRESSED to 61us — do not reintroduce without disasm evidence]
template <bool OUT_BF16>
__global__ __launch_bounds__(512, 2) void k_gemm_bt(
    const ushort_t* __restrict__ A,
    const ushort_t* __restrict__ Bt,
    const float* __restrict__ bias,   // [T, 1024]
    void* __restrict__ out,           // [T, 4096, 1024]
    const float* __restrict__ inte)   // [T, E] or null
{
    __shared__ __align__(16) char lds[131072];   // 2 buf x (A 32K + B 32K)

    // 256 blocks, 1/CU. XCD pair (2t, 2t+1) owns task t -> its 2MB B panel
    // stays resident in that XCD's L2.
    const int f = blockIdx.x;            // 0..255
    const int xcd = f & 7;
    const int tk = xcd >> 1;
    const int ib = f >> 3;               // 0..31 within XCD
    const int n_blk = ib & 3;
    const int m_blk = ((ib >> 2) << 1) | (xcd & 1);
    const int m0 = m_blk * 256, n0 = n_blk * 256;

    const ushort_t* Ap = A + (size_t)tk * B_ * D_;
    const ushort_t* Bp = Bt + (size_t)tk * D_ * D_;
    const float* bp = bias + tk * D_;

    const int tid = threadIdx.x;
    const int lane = tid & 63, wid = tid >> 6;     // 8 waves
    const int lr = lane & 15, quad = lane >> 4;
    const int wmt = (wid & 1) * 128;               // wave M offset in tile
    const int wnt = (wid >> 1) * 64;               // wave N offset in tile

    // read-side swizzled within-row byte offsets (row-dependent part is
    // (lr&7)<<4 since all row bases are multiples of 8 rows)
    const int swz = (lr & 7) << 4;
    const int kk0 = (quad * 16) ^ swz;             // kstep 0
    const int kk1 = (64 + quad * 16) ^ swz;        // kstep 1

    // staging: per half-tile (128 rows x 64 cols bf16 = 16 KB) each thread
    // issues 2 x 16B global_load_lds. LDS dest linear (base + lane*16);
    // global source column pre-swizzled with the same involution the reads use.
    const int q0 = tid, q1 = tid + 512;
    const ushort_t* gA0 = Ap + (size_t)(m0 + (q0 >> 3)) * D_ + 8 * ((q0 & 7) ^ ((q0 >> 3) & 7));
    const ushort_t* gA1 = Ap + (size_t)(m0 + (q1 >> 3)) * D_ + 8 * ((q1 & 7) ^ ((q1 >> 3) & 7));
    const ushort_t* gB0 = Bp + (size_t)(n0 + (q0 >> 3)) * D_ + 8 * ((q0 & 7) ^ ((q0 >> 3) & 7));
    const ushort_t* gB1 = Bp + (size_t)(n0 + (q1 >> 3)) * D_ + 8 * ((q1 & 7) ^ ((q1 >> 3) & 7));
    char* lA0 = lds + q0 * 16;
    char* lA1 = lds + q1 * 16;
    char* lB0 = lds + 32768 + q0 * 16;
    char* lB1 = lds + 32768 + q1 * 16;

#define STAGE_A(kt, h, s_)                                                     \
    do {                                                                       \
        GLOBAL_LOAD_LDS16(gA0 + (size_t)(h) * 131072 + (kt) * 64,              \
                          lA0 + (s_) * 65536 + (h) * 16384);                   \
        GLOBAL_LOAD_LDS16(gA1 + (size_t)(h) * 131072 + (kt) * 64,              \
                          lA1 + (s_) * 65536 + (h) * 16384);                   \
    } while (0)
#define STAGE_B(kt, h, s_)                                                     \
    do {                                                                       \
        GLOBAL_LOAD_LDS16(gB0 + (size_t)(h) * 131072 + (kt) * 64,              \
                          lB0 + (s_) * 65536 + (h) * 16384);                   \
        GLOBAL_LOAD_LDS16(gB1 + (size_t)(h) * 131072 + (kt) * 64,              \
                          lB1 + (s_) * 65536 + (h) * 16384);                   \
    } while (0)

    f32x4 acc[8][4] = {};

    // prologue: tile0 complete + tile1 A halves (12 loads); wait 8 oldest.
    STAGE_A(0, 0, 0); STAGE_A(0, 1, 0);
    STAGE_B(0, 0, 0); STAGE_B(0, 1, 0);
    STAGE_A(1, 0, 1); STAGE_A(1, 1, 1);
    asm volatile("s_waitcnt vmcnt(4)" ::: "memory");
    __builtin_amdgcn_s_barrier();
    __builtin_amdgcn_sched_barrier(0);

    // K loop: 16 tiles of BK=64. Issue schedule per tile t:
    //   p0: (t+1).B0   p1: (t+1).B1   p2: (t+2).A0   p3: (t+2).A1
    // Boundary ledger: carried 4 loads (= next tile's A halves) + 8 issued;
    // vmcnt(4) drains the 8 oldest -> tile t+1 fully landed, (t+2).A in flight.
    for (int t = 0; t < 16; ++t) {
        const int s = t & 1;
        const char* As_ = lds + s * 65536;
        const char* Bs_ = lds + s * 65536 + 32768;
        bf16x8 af0[4][2], af1[4][2], bfv[2][2];

        // ---- phase 0: read A(mi 0..3) + B(ni 0..1); stage (t+1).B0
#pragma unroll
        for (int mi = 0; mi < 4; ++mi) {
            af0[mi][0] = *(const bf16x8*)(As_ + (wmt + mi * 16 + lr) * 128 + kk0);
            af0[mi][1] = *(const bf16x8*)(As_ + (wmt + mi * 16 + lr) * 128 + kk1);
        }
#pragma unroll
        for (int ni = 0; ni < 2; ++ni) {
            bfv[ni][0] = *(const bf16x8*)(Bs_ + (wnt + ni * 16 + lr) * 128 + kk0);
            bfv[ni][1] = *(const bf16x8*)(Bs_ + (wnt + ni * 16 + lr) * 128 + kk1);
        }
        if (t + 1 < 16) STAGE_B(t + 1, 0, s ^ 1);
        __builtin_amdgcn_s_barrier();
        __builtin_amdgcn_s_setprio(1);
#pragma unroll
        for (int mi = 0; mi < 4; ++mi)
#pragma unroll
            for (int ni = 0; ni < 2; ++ni) {
                acc[mi][ni] = __builtin_amdgcn_mfma_f32_16x16x32_bf16(
                    af0[mi][0], bfv[ni][0], acc[mi][ni], 0, 0, 0);
                acc[mi][ni] = __builtin_amdgcn_mfma_f32_16x16x32_bf16(
                    af0[mi][1], bfv[ni][1], acc[mi][ni], 0, 0, 0);
            }
        __builtin_amdgcn_s_setprio(0);
        __builtin_amdgcn_s_barrier();

        // ---- phase 1: read A(mi 4..7); stage (t+1).B1
#pragma unroll
        for (int mi = 0; mi < 4; ++mi) {
            af1[mi][0] = *(const bf16x8*)(As_ + (wmt + 64 + mi * 16 + lr) * 128 + kk0);
            af1[mi][1] = *(const bf16x8*)(As_ + (wmt + 64 + mi * 16 + lr) * 128 + kk1);
        }
        if (t + 1 < 16) STAGE_B(t + 1, 1, s ^ 1);
        __builtin_amdgcn_s_barrier();
        __builtin_amdgcn_s_setprio(1);
#pragma unroll
        for (int mi = 0; mi < 4; ++mi)
#pragma unroll
            for (int ni = 0; ni < 2; ++ni) {
                acc[4 + mi][ni] = __builtin_amdgcn_mfma_f32_16x16x32_bf16(
                    af1[mi][0], bfv[ni][0], acc[4 + mi][ni], 0, 0, 0);
                acc[4 + mi][ni] = __builtin_amdgcn_mfma_f32_16x16x32_bf16(
                    af1[mi][1], bfv[ni][1], acc[4 + mi][ni], 0, 0, 0);
            }
        __builtin_amdgcn_s_setprio(0);
        __builtin_amdgcn_s_barrier();

        // ---- phase 2: read B(ni 2..3) (A halves of buf s now free); stage (t+2).A0
#pragma unroll
        for (int ni = 0; ni < 2; ++ni) {
            bfv[ni][0] = *(const bf16x8*)(Bs_ + (wnt + 32 + ni * 16 + lr) * 128 + kk0);
            bfv[ni][1] = *(const bf16x8*)(Bs_ + (wnt + 32 + ni * 16 + lr) * 128 + kk1);
        }
        if (t + 2 < 16) STAGE_A(t + 2, 0, s);
        __builtin_amdgcn_s_barrier();
        __builtin_amdgcn_s_setprio(1);
#pragma unroll
        for (int mi = 0; mi < 4; ++mi)
#pragma unroll
            for (int ni = 0; ni < 2; ++ni) {
                acc[4 + mi][2 + ni] = __builtin_amdgcn_mfma_f32_16x16x32_bf16(
                    af1[mi][0], bfv[ni][0], acc[4 + mi][2 + ni], 0, 0, 0);
                acc[4 + mi][2 + ni] = __builtin_amdgcn_mfma_f32_16x16x32_bf16(
                    af1[mi][1], bfv[ni][1], acc[4 + mi][2 + ni], 0, 0, 0);
            }
        __builtin_amdgcn_s_setprio(0);
        __builtin_amdgcn_s_barrier();

        // ---- phase 3: no ds_read (af0 + bfv resident); stage (t+2).A1
        if (t + 2 < 16) STAGE_A(t + 2, 1, s);
        __builtin_amdgcn_s_barrier();
        __builtin_amdgcn_s_setprio(1);
#pragma unroll
        for (int mi = 0; mi < 4; ++mi)
#pragma unroll
            for (int ni = 0; ni < 2; ++ni) {
                acc[mi][2 + ni] = __builtin_amdgcn_mfma_f32_16x16x32_bf16(
                    af0[mi][0], bfv[ni][0], acc[mi][2 + ni], 0, 0, 0);
                acc[mi][2 + ni] = __builtin_amdgcn_mfma_f32_16x16x32_bf16(
                    af0[mi][1], bfv[ni][1], acc[mi][2 + ni], 0, 0, 0);
            }
        __builtin_amdgcn_s_setprio(0);
        if (t < 14)       asm volatile("s_waitcnt vmcnt(4)" ::: "memory");
        else if (t == 14) asm volatile("s_waitcnt vmcnt(0)" ::: "memory");
        __builtin_amdgcn_s_barrier();
        __builtin_amdgcn_sched_barrier(0);
    }
#undef STAGE_A
#undef STAGE_B

    float scale = 1.0f;
    if (inte) {
        const float* ip = inte + tk * E_;
        scale = ip[0] + ip[1] + ip[2] + ip[3];
    }
#pragma unroll
    for (int mi = 0; mi < 8; ++mi) {
#pragma unroll
        for (int ni = 0; ni < 4; ++ni) {
            const int gcol = n0 + wnt + ni * 16 + lr;
            const float bv = bp[gcol];
#pragma unroll
            for (int r = 0; r < 4; ++r) {
                const int grow = m0 + wmt + mi * 16 + quad * 4 + r;
                float v = acc[mi][ni][r] + bv;
                v = fmaxf(v, 0.0f) * scale;
                const size_t off = (size_t)tk * B_ * D_ + (size_t)grow * D_ + gcol;
                if (OUT_BF16) ((ushort_t*)out)[off] = f2bf(v);
                else          ((float*)out)[off] = v;
            }
        }
    }
}

// gate + combine: one block per batch row b
template <bool FINAL>
__global__ __launch_bounds__(256) void k_gate_combine(
    const float* __restrict__ teo,  // [T, B, D] f32
    const float* __restrict__ Wg,   // [D, T] f32
    const float* __restrict__ bg,   // [T] f32
    void* __restrict__ out)         // FINAL: f32 [B,T,D]; else bf16 [T,B,D]
{
    const int b = blockIdx.x;
    const int tid = threadIdx.x;
    const int d0 = tid * 4;

    float4 tv[4];
#pragma unroll
    for (int t = 0; t < 4; ++t)
        tv[t] = *(const float4*)(teo + (size_t)t * B_ * D_ + (size_t)b * D_ + d0);
    float4 wg[4];
#pragma unroll
    for (int i = 0; i < 4; ++i)
        wg[i] = *(const float4*)(Wg + (size_t)(d0 + i) * 4);

    float p[16];
#pragma unroll
    for (int t = 0; t < 4; ++t) {
        const float* tvp = (const float*)&tv[t];
#pragma unroll
        for (int k = 0; k < 4; ++k) {
            p[t * 4 + k] = tvp[0] * ((const float*)&wg[0])[k]
                         + tvp[1] * ((const float*)&wg[1])[k]
                         + tvp[2] * ((const float*)&wg[2])[k]
                         + tvp[3] * ((const float*)&wg[3])[k];
        }
    }
#pragma unroll
    for (int i = 0; i < 16; ++i) {
        float v = p[i];
        v += __shfl_xor(v, 1, 64);
        v += __shfl_xor(v, 2, 64);
        v += __shfl_xor(v, 4, 64);
        v += __shfl_xor(v, 8, 64);
        p[i] = v;
    }
    __shared__ float red[16][16];
    __shared__ float fin[16];
    const int grp = tid >> 4;
    if ((tid & 15) == 0) {
#pragma unroll
        for (int i = 0; i < 16; ++i) red[grp][i] = p[i];
    }
    __syncthreads();
    if (tid < 16) {
        float v = 0.0f;
#pragma unroll
        for (int g = 0; g < 16; ++g) v += red[g][tid];
        fin[tid] = v;
    }
    __syncthreads();

    float g[4][4];
#pragma unroll
    for (int t = 0; t < 4; ++t) {
        float lg[4];
#pragma unroll
        for (int k = 0; k < 4; ++k)
            lg[k] = fin[t * 4 + k] + bg[k];
        float mx = fmaxf(fmaxf(lg[0], lg[1]), fmaxf(lg[2], lg[3]));
        float e0 = __expf(lg[0] - mx), e1 = __expf(lg[1] - mx);
        float e2 = __expf(lg[2] - mx), e3 = __expf(lg[3] - mx);
        float inv = 1.0f / (e0 + e1 + e2 + e3);
        g[t][0] = e0 * inv; g[t][1] = e1 * inv; g[t][2] = e2 * inv; g[t][3] = e3 * inv;
    }
#pragma unroll
    for (int t = 0; t < 4; ++t) {
        float o[4];
#pragma unroll
        for (int i = 0; i < 4; ++i) {
            o[i] = g[t][0] * ((const float*)&tv[0])[i]
                 + g[t][1] * ((const float*)&tv[1])[i]
                 + g[t][2] * ((const float*)&tv[2])[i]
                 + g[t][3] * ((const float*)&tv[3])[i]
                 + ((const float*)&tv[t])[i];
        }
        if (FINAL) {
            float4 ov = { o[0], o[1], o[2], o[3] };
            *(float4*)((float*)out + (size_t)b * T_ * D_ + (size_t)t * D_ + d0) = ov;
        } else {
            ushort4 ov = { f2bf(o[0]), f2bf(o[1]), f2bf(o[2]), f2bf(o[3]) };
            *(ushort4*)((ushort_t*)out + (size_t)t * B_ * D_ + (size_t)b * D_ + d0) = ov;
        }
    }
}

extern "C" void kernel_launch(void* const* d_in, const int* in_sizes, int n_in,
                              void* d_out, int out_size, void* d_ws, size_t ws_size,
                              hipStream_t stream) {
    const float* x    = (const float*)d_in[0];
    const float* W1   = (const float*)d_in[1];
    const float* b1   = (const float*)d_in[2];
    const float* W2   = (const float*)d_in[3];
    const float* b2   = (const float*)d_in[4];
    const float* inte = (const float*)d_in[5];
    const float* Wg   = (const float*)d_in[6];
    const float* bg   = (const float*)d_in[7];

    char* ws = (char*)d_ws;
    // ws layout (bytes): W1t 32M | W2t 32M | Hbf 32M | T1bf 32M | Teo 64M = 192 MiB
    ushort_t* W1t  = (ushort_t*)(ws);
    ushort_t* W2t  = (ushort_t*)(ws + 33554432);
    ushort_t* Hbf  = (ushort_t*)(ws + 67108864);
    ushort_t* T1bf = (ushort_t*)(ws + 100663296);
    float*    Teo  = (float*)   (ws + 134217728);

    // fused prep: blocks 0..4095 transpose W1/W2, 4096..12287 convert x
    k_prep<<<dim3(12288), 256, 0, stream>>>(x, W1, W2, Hbf, W1t, W2t);

    for (int l = 0; l < 2; ++l) {
        const size_t wOff = (size_t)l * T_ * D_ * D_;
        k_gemm_bt<true ><<<dim3(256), 512, 0, stream>>>(Hbf, W1t + wOff, b1 + l * T_ * D_,
                                                        (void*)T1bf, nullptr);
        k_gemm_bt<false><<<dim3(256), 512, 0, stream>>>(T1bf, W2t + wOff, b2 + l * T_ * D_,
                                                        (void*)Teo, inte + l * T_ * E_);
        if (l == 0)
            k_gate_combine<false><<<dim3(B_), 256, 0, stream>>>(
                Teo, Wg + l * D_ * T_, bg + l * T_, (void*)Hbf);
        else
            k_gate_combine<true ><<<dim3(B_), 256, 0, stream>>>(
                Teo, Wg + l * D_ * T_, bg + l * T_, (void*)d_out);
    }
}

// Round 13
// 349.223 us; speedup vs baseline: 1.0286x; 1.0286x over previous
//
#include <hip/hip_runtime.h>
#include <hip/hip_bf16.h>

#define B_ 4096
#define T_ 4
#define D_ 1024
#define E_ 4

typedef unsigned short ushort_t;
typedef float f32x4 __attribute__((ext_vector_type(4)));
typedef short bf16x8 __attribute__((ext_vector_type(8)));

__device__ __forceinline__ unsigned short f2bf(float f) {
    unsigned int u = __float_as_uint(f);
    u += 0x7FFF + ((u >> 16) & 1);   // round-to-nearest-even
    return (unsigned short)(u >> 16);
}

__device__ __forceinline__ float bf2f(ushort_t u) {
    return __uint_as_float(((unsigned int)u) << 16);
}

#define GLOBAL_LOAD_LDS16(gp, lp)                                                        \
    __builtin_amdgcn_global_load_lds((const __attribute__((address_space(1))) void*)(gp),\
                                     (__attribute__((address_space(3))) void*)(lp),      \
                                     16, 0, 0)

// Fused prep, one launch. Flat grid: blk<4096 -> W transpose (16 matrices x
// 256 64x64 tiles); blk>=4096 -> x convert (8192 chunks of 2048 f32).
// [r6/r11 lesson: two very different prep implementations both pin at ~58us /
//  2.3 TB/s (VALUBusy 11%->5.5% with no dur change) — NOT instruction- or
//  dispatch-bound; mechanism unidentified. Stop blind iteration here.]
__global__ __launch_bounds__(256) void k_prep(const float* __restrict__ x,
                                              const float* __restrict__ W1,
                                              const float* __restrict__ W2,
                                              ushort_t* __restrict__ hbf,
                                              ushort_t* __restrict__ W1t,
                                              ushort_t* __restrict__ W2t) {
    const int blk = blockIdx.x;
    const int tid = threadIdx.x;
    if (blk >= 4096) {
        // convert: x [B,T,D] f32 -> hbf [T,B,D] bf16; 2048 f32 per block
        const int base = ((blk - 4096) * 256 + tid) * 8;
        const float4 v0 = *(const float4*)(x + base);
        const float4 v1 = *(const float4*)(x + base + 4);
        bf16x8 o;
        o[0] = (short)f2bf(v0.x); o[1] = (short)f2bf(v0.y);
        o[2] = (short)f2bf(v0.z); o[3] = (short)f2bf(v0.w);
        o[4] = (short)f2bf(v1.x); o[5] = (short)f2bf(v1.y);
        o[6] = (short)f2bf(v1.z); o[7] = (short)f2bf(v1.w);
        const int d = base & (D_ - 1);
        const int t = (base >> 10) & 3;
        const int b = base >> 12;
        *(bf16x8*)(hbf + (size_t)t * B_ * D_ + (size_t)b * D_ + d) = o;
        return;
    }
    // transpose: W[z] [D,O] f32 -> Wt[z] [O,D] bf16, 64x64 tile per block
    const int z = blk >> 8;                 // 0..15
    const int ti = blk & 255;               // 16x16 tile grid
    const int o0 = (ti & 15) * 64, d0 = (ti >> 4) * 64;
    const float* src = (z < 8) ? (W1 + (size_t)z * D_ * D_) : (W2 + (size_t)(z - 8) * D_ * D_);
    ushort_t* dst = (z < 8) ? (W1t + (size_t)z * D_ * D_) : (W2t + (size_t)(z - 8) * D_ * D_);

    __shared__ float tile[64][65];
    const int c4 = tid & 15;                // float4 column 0..15
    const int r0 = tid >> 4;                // 0..15
#pragma unroll
    for (int j = 0; j < 4; ++j) {
        const int r = r0 + 16 * j;
        const float4 v = *(const float4*)(src + (size_t)(d0 + r) * D_ + o0 + c4 * 4);
        tile[r][c4 * 4 + 0] = v.x;
        tile[r][c4 * 4 + 1] = v.y;
        tile[r][c4 * 4 + 2] = v.z;
        tile[r][c4 * 4 + 3] = v.w;
    }
    __syncthreads();
    const int cg = tid & 7, ro = tid >> 3;  // cg: 8-col group, ro: 0..31
#pragma unroll
    for (int j = 0; j < 2; ++j) {
        const int o = ro + 32 * j;
        bf16x8 ov;
#pragma unroll
        for (int k = 0; k < 8; ++k) ov[k] = (short)f2bf(tile[cg * 8 + k][o]);
        *(bf16x8*)(dst + (size_t)(o0 + o) * D_ + d0 + cg * 8) = ov;
    }
}

// C[4096,1024] = relu(A * Bt^T + bias) [* scale], batched over tasks.
// 256x256 tile, BK=64, 8 waves (2M x 4N), 128 KiB LDS double-buffer.
// 4 phases/K-tile {ds_read subtile | stage half-tile | s_barrier | setprio(1)
// 16xMFMA setprio(0) | s_barrier}; ONE counted s_waitcnt vmcnt(4) per K-tile,
// T2 XOR swizzle (LDS dest linear, global source pre-swizzled, reads swizzled).
// [round-3 verified: 43.5us/dispatch, 790 TF. round-5 static-dbuf 2x-unroll
//  REGRESSED to 61us — do not reintroduce without disasm evidence]
template <bool OUT_BF16>
__global__ __launch_bounds__(512, 2) void k_gemm_bt(
    const ushort_t* __restrict__ A,
    const ushort_t* __restrict__ Bt,
    const float* __restrict__ bias,   // [T, 1024]
    void* __restrict__ out,           // [T, 4096, 1024]
    const float* __restrict__ inte)   // [T, E] or null
{
    __shared__ __align__(16) char lds[131072];   // 2 buf x (A 32K + B 32K)

    // 256 blocks, 1/CU. XCD pair (2t, 2t+1) owns task t -> its 2MB B panel
    // stays resident in that XCD's L2.
    const int f = blockIdx.x;            // 0..255
    const int xcd = f & 7;
    const int tk = xcd >> 1;
    const int ib = f >> 3;               // 0..31 within XCD
    const int n_blk = ib & 3;
    const int m_blk = ((ib >> 2) << 1) | (xcd & 1);
    const int m0 = m_blk * 256, n0 = n_blk * 256;

    const ushort_t* Ap = A + (size_t)tk * B_ * D_;
    const ushort_t* Bp = Bt + (size_t)tk * D_ * D_;
    const float* bp = bias + tk * D_;

    const int tid = threadIdx.x;
    const int lane = tid & 63, wid = tid >> 6;     // 8 waves
    const int lr = lane & 15, quad = lane >> 4;
    const int wmt = (wid & 1) * 128;               // wave M offset in tile
    const int wnt = (wid >> 1) * 64;               // wave N offset in tile

    // read-side swizzled within-row byte offsets (row-dependent part is
    // (lr&7)<<4 since all row bases are multiples of 8 rows)
    const int swz = (lr & 7) << 4;
    const int kk0 = (quad * 16) ^ swz;             // kstep 0
    const int kk1 = (64 + quad * 16) ^ swz;        // kstep 1

    // staging: per half-tile (128 rows x 64 cols bf16 = 16 KB) each thread
    // issues 2 x 16B global_load_lds. LDS dest linear (base + lane*16);
    // global source column pre-swizzled with the same involution the reads use.
    const int q0 = tid, q1 = tid + 512;
    const ushort_t* gA0 = Ap + (size_t)(m0 + (q0 >> 3)) * D_ + 8 * ((q0 & 7) ^ ((q0 >> 3) & 7));
    const ushort_t* gA1 = Ap + (size_t)(m0 + (q1 >> 3)) * D_ + 8 * ((q1 & 7) ^ ((q1 >> 3) & 7));
    const ushort_t* gB0 = Bp + (size_t)(n0 + (q0 >> 3)) * D_ + 8 * ((q0 & 7) ^ ((q0 >> 3) & 7));
    const ushort_t* gB1 = Bp + (size_t)(n0 + (q1 >> 3)) * D_ + 8 * ((q1 & 7) ^ ((q1 >> 3) & 7));
    char* lA0 = lds + q0 * 16;
    char* lA1 = lds + q1 * 16;
    char* lB0 = lds + 32768 + q0 * 16;
    char* lB1 = lds + 32768 + q1 * 16;

#define STAGE_A(kt, h, s_)                                                     \
    do {                                                                       \
        GLOBAL_LOAD_LDS16(gA0 + (size_t)(h) * 131072 + (kt) * 64,              \
                          lA0 + (s_) * 65536 + (h) * 16384);                   \
        GLOBAL_LOAD_LDS16(gA1 + (size_t)(h) * 131072 + (kt) * 64,              \
                          lA1 + (s_) * 65536 + (h) * 16384);                   \
    } while (0)
#define STAGE_B(kt, h, s_)                                                     \
    do {                                                                       \
        GLOBAL_LOAD_LDS16(gB0 + (size_t)(h) * 131072 + (kt) * 64,              \
                          lB0 + (s_) * 65536 + (h) * 16384);                   \
        GLOBAL_LOAD_LDS16(gB1 + (size_t)(h) * 131072 + (kt) * 64,              \
                          lB1 + (s_) * 65536 + (h) * 16384);                   \
    } while (0)

    f32x4 acc[8][4] = {};

    // prologue: tile0 complete + tile1 A halves (12 loads); wait 8 oldest.
    STAGE_A(0, 0, 0); STAGE_A(0, 1, 0);
    STAGE_B(0, 0, 0); STAGE_B(0, 1, 0);
    STAGE_A(1, 0, 1); STAGE_A(1, 1, 1);
    asm volatile("s_waitcnt vmcnt(4)" ::: "memory");
    __builtin_amdgcn_s_barrier();
    __builtin_amdgcn_sched_barrier(0);

    // K loop: 16 tiles of BK=64. Issue schedule per tile t:
    //   p0: (t+1).B0   p1: (t+1).B1   p2: (t+2).A0   p3: (t+2).A1
    // Boundary ledger: carried 4 loads (= next tile's A halves) + 8 issued;
    // vmcnt(4) drains the 8 oldest -> tile t+1 fully landed, (t+2).A in flight.
    for (int t = 0; t < 16; ++t) {
        const int s = t & 1;
        const char* As_ = lds + s * 65536;
        const char* Bs_ = lds + s * 65536 + 32768;
        bf16x8 af0[4][2], af1[4][2], bfv[2][2];

        // ---- phase 0: read A(mi 0..3) + B(ni 0..1); stage (t+1).B0
#pragma unroll
        for (int mi = 0; mi < 4; ++mi) {
            af0[mi][0] = *(const bf16x8*)(As_ + (wmt + mi * 16 + lr) * 128 + kk0);
            af0[mi][1] = *(const bf16x8*)(As_ + (wmt + mi * 16 + lr) * 128 + kk1);
        }
#pragma unroll
        for (int ni = 0; ni < 2; ++ni) {
            bfv[ni][0] = *(const bf16x8*)(Bs_ + (wnt + ni * 16 + lr) * 128 + kk0);
            bfv[ni][1] = *(const bf16x8*)(Bs_ + (wnt + ni * 16 + lr) * 128 + kk1);
        }
        if (t + 1 < 16) STAGE_B(t + 1, 0, s ^ 1);
        __builtin_amdgcn_s_barrier();
        __builtin_amdgcn_s_setprio(1);
#pragma unroll
        for (int mi = 0; mi < 4; ++mi)
#pragma unroll
            for (int ni = 0; ni < 2; ++ni) {
                acc[mi][ni] = __builtin_amdgcn_mfma_f32_16x16x32_bf16(
                    af0[mi][0], bfv[ni][0], acc[mi][ni], 0, 0, 0);
                acc[mi][ni] = __builtin_amdgcn_mfma_f32_16x16x32_bf16(
                    af0[mi][1], bfv[ni][1], acc[mi][ni], 0, 0, 0);
            }
        __builtin_amdgcn_s_setprio(0);
        __builtin_amdgcn_s_barrier();

        // ---- phase 1: read A(mi 4..7); stage (t+1).B1
#pragma unroll
        for (int mi = 0; mi < 4; ++mi) {
            af1[mi][0] = *(const bf16x8*)(As_ + (wmt + 64 + mi * 16 + lr) * 128 + kk0);
            af1[mi][1] = *(const bf16x8*)(As_ + (wmt + 64 + mi * 16 + lr) * 128 + kk1);
        }
        if (t + 1 < 16) STAGE_B(t + 1, 1, s ^ 1);
        __builtin_amdgcn_s_barrier();
        __builtin_amdgcn_s_setprio(1);
#pragma unroll
        for (int mi = 0; mi < 4; ++mi)
#pragma unroll
            for (int ni = 0; ni < 2; ++ni) {
                acc[4 + mi][ni] = __builtin_amdgcn_mfma_f32_16x16x32_bf16(
                    af1[mi][0], bfv[ni][0], acc[4 + mi][ni], 0, 0, 0);
                acc[4 + mi][ni] = __builtin_amdgcn_mfma_f32_16x16x32_bf16(
                    af1[mi][1], bfv[ni][1], acc[4 + mi][ni], 0, 0, 0);
            }
        __builtin_amdgcn_s_setprio(0);
        __builtin_amdgcn_s_barrier();

        // ---- phase 2: read B(ni 2..3) (A halves of buf s now free); stage (t+2).A0
#pragma unroll
        for (int ni = 0; ni < 2; ++ni) {
            bfv[ni][0] = *(const bf16x8*)(Bs_ + (wnt + 32 + ni * 16 + lr) * 128 + kk0);
            bfv[ni][1] = *(const bf16x8*)(Bs_ + (wnt + 32 + ni * 16 + lr) * 128 + kk1);
        }
        if (t + 2 < 16) STAGE_A(t + 2, 0, s);
        __builtin_amdgcn_s_barrier();
        __builtin_amdgcn_s_setprio(1);
#pragma unroll
        for (int mi = 0; mi < 4; ++mi)
#pragma unroll
            for (int ni = 0; ni < 2; ++ni) {
                acc[4 + mi][2 + ni] = __builtin_amdgcn_mfma_f32_16x16x32_bf16(
                    af1[mi][0], bfv[ni][0], acc[4 + mi][2 + ni], 0, 0, 0);
                acc[4 + mi][2 + ni] = __builtin_amdgcn_mfma_f32_16x16x32_bf16(
                    af1[mi][1], bfv[ni][1], acc[4 + mi][2 + ni], 0, 0, 0);
            }
        __builtin_amdgcn_s_setprio(0);
        __builtin_amdgcn_s_barrier();

        // ---- phase 3: no ds_read (af0 + bfv resident); stage (t+2).A1
        if (t + 2 < 16) STAGE_A(t + 2, 1, s);
        __builtin_amdgcn_s_barrier();
        __builtin_amdgcn_s_setprio(1);
#pragma unroll
        for (int mi = 0; mi < 4; ++mi)
#pragma unroll
            for (int ni = 0; ni < 2; ++ni) {
                acc[mi][2 + ni] = __builtin_amdgcn_mfma_f32_16x16x32_bf16(
                    af0[mi][0], bfv[ni][0], acc[mi][2 + ni], 0, 0, 0);
                acc[mi][2 + ni] = __builtin_amdgcn_mfma_f32_16x16x32_bf16(
                    af0[mi][1], bfv[ni][1], acc[mi][2 + ni], 0, 0, 0);
            }
        __builtin_amdgcn_s_setprio(0);
        if (t < 14)       asm volatile("s_waitcnt vmcnt(4)" ::: "memory");
        else if (t == 14) asm volatile("s_waitcnt vmcnt(0)" ::: "memory");
        __builtin_amdgcn_s_barrier();
        __builtin_amdgcn_sched_barrier(0);
    }
#undef STAGE_A
#undef STAGE_B

    float scale = 1.0f;
    if (inte) {
        const float* ip = inte + tk * E_;
        scale = ip[0] + ip[1] + ip[2] + ip[3];
    }
#pragma unroll
    for (int mi = 0; mi < 8; ++mi) {
#pragma unroll
        for (int ni = 0; ni < 4; ++ni) {
            const int gcol = n0 + wnt + ni * 16 + lr;
            const float bv = bp[gcol];
#pragma unroll
            for (int r = 0; r < 4; ++r) {
                const int grow = m0 + wmt + mi * 16 + quad * 4 + r;
                float v = acc[mi][ni][r] + bv;
                v = fmaxf(v, 0.0f) * scale;
                const size_t off = (size_t)tk * B_ * D_ + (size_t)grow * D_ + gcol;
                if (OUT_BF16) ((ushort_t*)out)[off] = f2bf(v);
                else          ((float*)out)[off] = v;
            }
        }
    }
}

// gate + combine: one block per batch row b. Teo is now bf16 [T,B,D] (r12:
// halves the dominant Teo traffic; all gate/combine math stays f32 —
// declared absmax gamble ~0.002 -> ~0.004).
template <bool FINAL>
__global__ __launch_bounds__(256) void k_gate_combine(
    const ushort_t* __restrict__ teo,  // [T, B, D] bf16
    const float* __restrict__ Wg,      // [D, T] f32
    const float* __restrict__ bg,      // [T] f32
    void* __restrict__ out)            // FINAL: f32 [B,T,D]; else bf16 [T,B,D]
{
    const int b = blockIdx.x;
    const int tid = threadIdx.x;
    const int d0 = tid * 4;

    float4 tv[4];
#pragma unroll
    for (int t = 0; t < 4; ++t) {
        const ushort4 r = *(const ushort4*)(teo + (size_t)t * B_ * D_ + (size_t)b * D_ + d0);
        tv[t] = { bf2f(r.x), bf2f(r.y), bf2f(r.z), bf2f(r.w) };
    }
    float4 wg[4];
#pragma unroll
    for (int i = 0; i < 4; ++i)
        wg[i] = *(const float4*)(Wg + (size_t)(d0 + i) * 4);

    float p[16];
#pragma unroll
    for (int t = 0; t < 4; ++t) {
        const float* tvp = (const float*)&tv[t];
#pragma unroll
        for (int k = 0; k < 4; ++k) {
            p[t * 4 + k] = tvp[0] * ((const float*)&wg[0])[k]
                         + tvp[1] * ((const float*)&wg[1])[k]
                         + tvp[2] * ((const float*)&wg[2])[k]
                         + tvp[3] * ((const float*)&wg[3])[k];
        }
    }
#pragma unroll
    for (int i = 0; i < 16; ++i) {
        float v = p[i];
        v += __shfl_xor(v, 1, 64);
        v += __shfl_xor(v, 2, 64);
        v += __shfl_xor(v, 4, 64);
        v += __shfl_xor(v, 8, 64);
        p[i] = v;
    }
    __shared__ float red[16][16];
    __shared__ float fin[16];
    const int grp = tid >> 4;
    if ((tid & 15) == 0) {
#pragma unroll
        for (int i = 0; i < 16; ++i) red[grp][i] = p[i];
    }
    __syncthreads();
    if (tid < 16) {
        float v = 0.0f;
#pragma unroll
        for (int g = 0; g < 16; ++g) v += red[g][tid];
        fin[tid] = v;
    }
    __syncthreads();

    float g[4][4];
#pragma unroll
    for (int t = 0; t < 4; ++t) {
        float lg[4];
#pragma unroll
        for (int k = 0; k < 4; ++k)
            lg[k] = fin[t * 4 + k] + bg[k];
        float mx = fmaxf(fmaxf(lg[0], lg[1]), fmaxf(lg[2], lg[3]));
        float e0 = __expf(lg[0] - mx), e1 = __expf(lg[1] - mx);
        float e2 = __expf(lg[2] - mx), e3 = __expf(lg[3] - mx);
        float inv = 1.0f / (e0 + e1 + e2 + e3);
        g[t][0] = e0 * inv; g[t][1] = e1 * inv; g[t][2] = e2 * inv; g[t][3] = e3 * inv;
    }
#pragma unroll
    for (int t = 0; t < 4; ++t) {
        float o[4];
#pragma unroll
        for (int i = 0; i < 4; ++i) {
            o[i] = g[t][0] * ((const float*)&tv[0])[i]
                 + g[t][1] * ((const float*)&tv[1])[i]
                 + g[t][2] * ((const float*)&tv[2])[i]
                 + g[t][3] * ((const float*)&tv[3])[i]
                 + ((const float*)&tv[t])[i];
        }
        if (FINAL) {
            float4 ov = { o[0], o[1], o[2], o[3] };
            *(float4*)((float*)out + (size_t)b * T_ * D_ + (size_t)t * D_ + d0) = ov;
        } else {
            ushort4 ov = { f2bf(o[0]), f2bf(o[1]), f2bf(o[2]), f2bf(o[3]) };
            *(ushort4*)((ushort_t*)out + (size_t)t * B_ * D_ + (size_t)b * D_ + d0) = ov;
        }
    }
}

extern "C" void kernel_launch(void* const* d_in, const int* in_sizes, int n_in,
                              void* d_out, int out_size, void* d_ws, size_t ws_size,
                              hipStream_t stream) {
    const float* x    = (const float*)d_in[0];
    const float* W1   = (const float*)d_in[1];
    const float* b1   = (const float*)d_in[2];
    const float* W2   = (const float*)d_in[3];
    const float* b2   = (const float*)d_in[4];
    const float* inte = (const float*)d_in[5];
    const float* Wg   = (const float*)d_in[6];
    const float* bg   = (const float*)d_in[7];

    char* ws = (char*)d_ws;
    // ws layout (bytes): W1t 32M | W2t 32M | Hbf 32M | T1bf 32M | Teo 32M (bf16)
    ushort_t* W1t  = (ushort_t*)(ws);
    ushort_t* W2t  = (ushort_t*)(ws + 33554432);
    ushort_t* Hbf  = (ushort_t*)(ws + 67108864);
    ushort_t* T1bf = (ushort_t*)(ws + 100663296);
    ushort_t* Teo  = (ushort_t*)(ws + 134217728);

    // fused prep: blocks 0..4095 transpose W1/W2, 4096..12287 convert x
    k_prep<<<dim3(12288), 256, 0, stream>>>(x, W1, W2, Hbf, W1t, W2t);

    for (int l = 0; l < 2; ++l) {
        const size_t wOff = (size_t)l * T_ * D_ * D_;
        k_gemm_bt<true><<<dim3(256), 512, 0, stream>>>(Hbf, W1t + wOff, b1 + l * T_ * D_,
                                                       (void*)T1bf, nullptr);
        k_gemm_bt<true><<<dim3(256), 512, 0, stream>>>(T1bf, W2t + wOff, b2 + l * T_ * D_,
                                                       (void*)Teo, inte + l * T_ * E_);
        if (l == 0)
            k_gate_combine<false><<<dim3(B_), 256, 0, stream>>>(
                Teo, Wg + l * D_ * T_, bg + l * T_, (void*)Hbf);
        else
            k_gate_combine<true ><<<dim3(B_), 256, 0, stream>>>(
                Teo, Wg + l * D_ * T_, bg + l * T_, (void*)d_out);
    }
}